// Round 2
// baseline (345.494 us; speedup 1.0000x reference)
//
#include <hip/hip_runtime.h>
#include <hip/hip_bf16.h>

typedef short bf16x8 __attribute__((ext_vector_type(8)));
typedef float f32x4 __attribute__((ext_vector_type(4)));

#define MFMA16(a, b, c) __builtin_amdgcn_mfma_f32_16x16x32_bf16(a, b, c, 0, 0, 0)

static constexpr int SEQ = 1024;   // L
static constexpr int DIM = 1024;
static constexpr int NH = 16;
static constexpr int HD = 64;

// ---------------------------------------------------------------------------
// fp32 -> bf16 conversion (RNE), 4 elements per thread, n % 4 == 0
// ---------------------------------------------------------------------------
__global__ __launch_bounds__(256) void cvt_f32_bf16(
    const float* __restrict__ src, __hip_bfloat16* __restrict__ dst, int n)
{
    const int i = (blockIdx.x * 256 + threadIdx.x) * 4;
    if (i < n) {
        float4 v = *(const float4*)(src + i);
        __hip_bfloat16 t[4];
        t[0] = __float2bfloat16(v.x);
        t[1] = __float2bfloat16(v.y);
        t[2] = __float2bfloat16(v.z);
        t[3] = __float2bfloat16(v.w);
        *(ushort4*)(dst + i) = *(ushort4*)t;
    }
}

// ---------------------------------------------------------------------------
// GEMM: Y[m,n] = sum_k X[m,k] * W[n,k] + bias[n]   (torch Linear, W row-major (N,K))
// Block = 256 thr (4 waves). Block tile 64x64; wave tile 16 rows x 64 cols.
// A-frag: A[m=lane&15][k=quad*8+j]  -> 16B contiguous from X row.
// B-frag: B[k][n]=W[n][k], lane n=lane&15 -> 16B contiguous from W row.
// C/D:    col=lane&15, row=quad*4+r   (verified layout, learn_hip m89/m91)
// ---------------------------------------------------------------------------
template <typename OutT>
__global__ __launch_bounds__(256) void gemm_bt(
    const __hip_bfloat16* __restrict__ X,   // M x K (bf16)
    const __hip_bfloat16* __restrict__ W,   // N x K (bf16)
    const float* __restrict__ bias,         // N (fp32)
    OutT* __restrict__ Y,                   // M x N
    int M, int N, int K)
{
    const int wave  = threadIdx.x >> 6;
    const int lane  = threadIdx.x & 63;
    const int col16 = lane & 15;
    const int quad  = lane >> 4;

    const int m0 = blockIdx.x * 64 + wave * 16;
    const int n0 = blockIdx.y * 64;

    f32x4 acc[4] = {};

    const __hip_bfloat16* arow = X + (size_t)(m0 + col16) * K + quad * 8;
    const __hip_bfloat16* brow = W + (size_t)(n0 + col16) * K + quad * 8;

    for (int k0 = 0; k0 < K; k0 += 32) {
        bf16x8 af = *(const bf16x8*)(arow + k0);
#pragma unroll
        for (int t = 0; t < 4; ++t) {
            bf16x8 bfr = *(const bf16x8*)(brow + (size_t)t * 16 * K + k0);
            acc[t] = MFMA16(af, bfr, acc[t]);
        }
    }

#pragma unroll
    for (int t = 0; t < 4; ++t) {
        const int n = n0 + t * 16 + col16;
        const float bv = bias[n];
#pragma unroll
        for (int r = 0; r < 4; ++r) {
            const int m = m0 + quad * 4 + r;
            Y[(size_t)m * N + n] = (OutT)(acc[t][r] + bv);
        }
    }
}

// ---------------------------------------------------------------------------
// Attention: per block = 64 q-rows of one (b,h). 4 waves x 16 rows.
// Streams j in tiles of 32: sim = Q K^T (MFMA), scores = sum_f a*sin(c*sim+phi),
// w = sigmoid(scores); accumulate O += P V (MFMA) and denom += sum_j w.
// P transforms C-layout -> A-layout through per-wave LDS. V tile staged
// transposed in LDS so PV B-frags are contiguous 16B reads.
// ---------------------------------------------------------------------------
__global__ __launch_bounds__(256) void attn_kernel(
    const __hip_bfloat16* __restrict__ Q,
    const __hip_bfloat16* __restrict__ K,
    const __hip_bfloat16* __restrict__ V,
    const float* __restrict__ alpha,        // (NH,5) fp32
    const float* __restrict__ phi,          // (NH,5) fp32
    const float* __restrict__ temperature,  // (1,)  fp32
    __hip_bfloat16* __restrict__ AO)        // (B*L, DIM)
{
    __shared__ __align__(16) __hip_bfloat16 Vt[HD][40];       // Vt[d][jj], padded
    __shared__ __align__(16) __hip_bfloat16 Pl[4][16][40];    // per-wave P tile

    const int wave  = threadIdx.x >> 6;
    const int lane  = threadIdx.x & 63;
    const int col16 = lane & 15;
    const int quad  = lane >> 4;

    const int bh = blockIdx.y;
    const int b  = bh >> 4;
    const int h  = bh & 15;
    const int i0 = blockIdx.x * 64 + wave * 16;

    const size_t base = ((size_t)b * SEQ) * DIM + (size_t)h * HD; // row stride DIM

    const float tempv    = fabsf(temperature[0]) + 0.1f;
    const float simscale = 1.0f / (8.0f * tempv);

    const float freqs[5] = {31.0f, 37.0f, 41.0f, 43.0f, 47.0f};
    float al[5], ph[5], cf[5];
#pragma unroll
    for (int f = 0; f < 5; ++f) {
        al[f] = alpha[h * 5 + f];
        ph[f] = phi[h * 5 + f];
        cf[f] = 6.283185307f * simscale / freqs[f];
    }

    // Q fragments (invariant over j): rows i0..i0+15, k 0..63
    const __hip_bfloat16* qrow = Q + base + (size_t)(i0 + col16) * DIM + quad * 8;
    const bf16x8 qa0 = *(const bf16x8*)(qrow);
    const bf16x8 qa1 = *(const bf16x8*)(qrow + 32);

    f32x4 o[4] = {};
    float denom[4] = {0.f, 0.f, 0.f, 0.f};

    for (int j0 = 0; j0 < SEQ; j0 += 32) {
        __syncthreads();
        // cooperative transposed V-tile load: 256 thr x 8 elems
        {
            const int jj = threadIdx.x >> 3;          // 0..31
            const int c0 = (threadIdx.x & 7) * 8;     // 0..56
            const __hip_bfloat16* vp = V + base + (size_t)(j0 + jj) * DIM + c0;
            bf16x8 vv = *(const bf16x8*)vp;
#pragma unroll
            for (int e = 0; e < 8; ++e)
                Vt[c0 + e][jj] = ((const __hip_bfloat16*)&vv)[e];
        }
        __syncthreads();

        // sim tiles (2 sub-tiles of 16 j-cols) + transform + P store
#pragma unroll
        for (int s = 0; s < 2; ++s) {
            const __hip_bfloat16* krow =
                K + base + (size_t)(j0 + s * 16 + col16) * DIM + quad * 8;
            bf16x8 kb0 = *(const bf16x8*)(krow);
            bf16x8 kb1 = *(const bf16x8*)(krow + 32);
            f32x4 sa = {};
            sa = MFMA16(qa0, kb0, sa);
            sa = MFMA16(qa1, kb1, sa);
#pragma unroll
            for (int r = 0; r < 4; ++r) {
                const float sv = sa[r]; // raw q.k; scale folded into cf
                float sc = 0.f;
#pragma unroll
                for (int f = 0; f < 5; ++f)
                    sc += al[f] * __sinf(sv * cf[f] + ph[f]);
                const float w = 1.0f / (1.0f + __expf(-sc));
                denom[r] += w;
                Pl[wave][quad * 4 + r][s * 16 + col16] = __float2bfloat16(w);
            }
        }

        // P (A-layout) x V (B-layout from Vt)
        bf16x8 pa = *(const bf16x8*)(&Pl[wave][col16][quad * 8]);
#pragma unroll
        for (int t = 0; t < 4; ++t) {
            bf16x8 vb = *(const bf16x8*)(&Vt[t * 16 + col16][quad * 8]);
            o[t] = MFMA16(pa, vb, o[t]);
        }
    }

    // denom reduction across the 16-lane column group (butterfly -> all lanes)
#pragma unroll
    for (int r = 0; r < 4; ++r) {
        float d = denom[r];
        d += __shfl_xor(d, 1);
        d += __shfl_xor(d, 2);
        d += __shfl_xor(d, 4);
        d += __shfl_xor(d, 8);
        denom[r] = d + 1e-10f;
    }

#pragma unroll
    for (int t = 0; t < 4; ++t) {
#pragma unroll
        for (int r = 0; r < 4; ++r) {
            const size_t row = (size_t)b * SEQ + i0 + quad * 4 + r;
            AO[row * DIM + h * HD + t * 16 + col16] =
                __float2bfloat16(o[t][r] / denom[r]);
        }
    }
}

// ---------------------------------------------------------------------------
// LayerNorm over last dim (1024), eps=1e-5, biased variance. fp32 in/out.
// One block (256 thr) per row; each thread owns 4 strided elements.
// ---------------------------------------------------------------------------
__global__ __launch_bounds__(256) void ln_kernel(
    const float* __restrict__ Yp,
    const float* __restrict__ gamma,
    const float* __restrict__ beta,
    float* __restrict__ out)
{
    const int row = blockIdx.x;
    const float* y = Yp + (size_t)row * DIM;

    float v[4];
    float s = 0.f, s2 = 0.f;
#pragma unroll
    for (int e = 0; e < 4; ++e) {
        v[e] = y[threadIdx.x + e * 256];
        s  += v[e];
        s2 += v[e] * v[e];
    }
#pragma unroll
    for (int off = 1; off < 64; off <<= 1) {
        s  += __shfl_xor(s, off);
        s2 += __shfl_xor(s2, off);
    }
    __shared__ float ps[4], ps2[4];
    const int wave = threadIdx.x >> 6;
    if ((threadIdx.x & 63) == 0) { ps[wave] = s; ps2[wave] = s2; }
    __syncthreads();
    s  = ps[0] + ps[1] + ps[2] + ps[3];
    s2 = ps2[0] + ps2[1] + ps2[2] + ps2[3];

    const float mu   = s * (1.0f / DIM);
    const float var  = s2 * (1.0f / DIM) - mu * mu;
    const float rstd = rsqrtf(var + 1e-5f);

#pragma unroll
    for (int e = 0; e < 4; ++e) {
        const int idx = threadIdx.x + e * 256;
        out[(size_t)row * DIM + idx] =
            (v[e] - mu) * rstd * gamma[idx] + beta[idx];
    }
}

// ---------------------------------------------------------------------------
extern "C" void kernel_launch(void* const* d_in, const int* in_sizes, int n_in,
                              void* d_out, int out_size, void* d_ws, size_t ws_size,
                              hipStream_t stream)
{
    const float* x     = (const float*)d_in[0];
    const float* Wq    = (const float*)d_in[1];
    const float* bq    = (const float*)d_in[2];
    const float* Wk    = (const float*)d_in[3];
    const float* bk    = (const float*)d_in[4];
    const float* Wv    = (const float*)d_in[5];
    const float* bv    = (const float*)d_in[6];
    const float* Wo    = (const float*)d_in[7];
    const float* bo    = (const float*)d_in[8];
    const float* alpha = (const float*)d_in[9];
    const float* phi   = (const float*)d_in[10];
    const float* temp  = (const float*)d_in[11];
    const float* gamma = (const float*)d_in[12];
    const float* beta  = (const float*)d_in[13];

    float* out = (float*)d_out;

    const int B = 2;
    const int M = B * SEQ;                 // 2048
    const size_t NX = (size_t)M * DIM;     // 2M elements
    const size_t NW = (size_t)DIM * DIM;   // 1M elements

    // ws layout (bytes):
    //   [0,4M)   xb   (2M bf16)        } dead after QKV gemms
    //   [4M,6M)  Wqb  (1M bf16)        } dead after gemm Q
    //   [6M,8M)  Wkb  (1M bf16)        } dead after gemm K
    //   [8M,10M) Wvb  (1M bf16)
    //   [10M,12M)Wob  (1M bf16)
    //   [12M,16M)Qb   (2M bf16)
    //   [16M,20M)Kb   (2M bf16)
    //   [20M,24M)Vb   (2M bf16)
    //   [24M,28M)AO   (2M bf16)
    //   Yp (2M fp32, 8MB) aliases [0,8M) — xb/Wqb/Wkb, all dead by O-proj.
    char* wsb = (char*)d_ws;
    __hip_bfloat16* xb  = (__hip_bfloat16*)(wsb + 0);
    __hip_bfloat16* Wqb = (__hip_bfloat16*)(wsb + (4u << 20));
    __hip_bfloat16* Wkb = (__hip_bfloat16*)(wsb + (6u << 20));
    __hip_bfloat16* Wvb = (__hip_bfloat16*)(wsb + (8u << 20));
    __hip_bfloat16* Wob = (__hip_bfloat16*)(wsb + (10u << 20));
    __hip_bfloat16* Qb  = (__hip_bfloat16*)(wsb + (12u << 20));
    __hip_bfloat16* Kb  = (__hip_bfloat16*)(wsb + (16u << 20));
    __hip_bfloat16* Vb  = (__hip_bfloat16*)(wsb + (20u << 20));
    __hip_bfloat16* AO  = (__hip_bfloat16*)(wsb + (24u << 20));
    float*          Yp  = (float*)(wsb + 0);

    // fp32 -> bf16 conversions
    hipLaunchKernelGGL(cvt_f32_bf16, dim3((int)(NX / 1024)), dim3(256), 0, stream, x,  xb,  (int)NX);
    hipLaunchKernelGGL(cvt_f32_bf16, dim3((int)(NW / 1024)), dim3(256), 0, stream, Wq, Wqb, (int)NW);
    hipLaunchKernelGGL(cvt_f32_bf16, dim3((int)(NW / 1024)), dim3(256), 0, stream, Wk, Wkb, (int)NW);
    hipLaunchKernelGGL(cvt_f32_bf16, dim3((int)(NW / 1024)), dim3(256), 0, stream, Wv, Wvb, (int)NW);
    hipLaunchKernelGGL(cvt_f32_bf16, dim3((int)(NW / 1024)), dim3(256), 0, stream, Wo, Wob, (int)NW);

    dim3 gblk(256), ggrid(M / 64, DIM / 64);
    hipLaunchKernelGGL((gemm_bt<__hip_bfloat16>), ggrid, gblk, 0, stream, xb, Wqb, bq, Qb, M, DIM, DIM);
    hipLaunchKernelGGL((gemm_bt<__hip_bfloat16>), ggrid, gblk, 0, stream, xb, Wkb, bk, Kb, M, DIM, DIM);
    hipLaunchKernelGGL((gemm_bt<__hip_bfloat16>), ggrid, gblk, 0, stream, xb, Wvb, bv, Vb, M, DIM, DIM);

    dim3 agrid(SEQ / 64, B * NH);
    hipLaunchKernelGGL(attn_kernel, agrid, dim3(256), 0, stream,
                       Qb, Kb, Vb, alpha, phi, temp, AO);

    hipLaunchKernelGGL((gemm_bt<float>), ggrid, gblk, 0, stream, AO, Wob, bo, Yp, M, DIM, DIM);

    hipLaunchKernelGGL(ln_kernel, dim3(M), dim3(256), 0, stream, Yp, gamma, beta, out);
}

// Round 3
// 198.218 us; speedup vs baseline: 1.7430x; 1.7430x over previous
//
#include <hip/hip_runtime.h>
#include <hip/hip_bf16.h>

typedef short bf16x8 __attribute__((ext_vector_type(8)));
typedef float f32x4 __attribute__((ext_vector_type(4)));

#define MFMA16(a, b, c) __builtin_amdgcn_mfma_f32_16x16x32_bf16(a, b, c, 0, 0, 0)

static constexpr int SEQ = 1024;
static constexpr int DIM = 1024;
static constexpr int NH = 16;
static constexpr int HD = 64;

#if __has_builtin(__builtin_amdgcn_sinf)
#define SIN_REV(x) __builtin_amdgcn_sinf(x)      // sin(2*pi*x), x in revolutions
#else
#define SIN_REV(x) __sinf((x) * 6.28318530718f)
#endif

#if __has_builtin(__builtin_amdgcn_rcpf)
#define FAST_RCP(x) __builtin_amdgcn_rcpf(x)
#else
#define FAST_RCP(x) (1.0f / (x))
#endif

// async 16B/lane global->LDS; lds dest = l + lane*16 bytes (HW semantics)
__device__ __forceinline__ void stage16(const __hip_bfloat16* g, __hip_bfloat16* l, int lane) {
#if __has_builtin(__builtin_amdgcn_global_load_lds)
    __builtin_amdgcn_global_load_lds(
        (const __attribute__((address_space(1))) unsigned int*)g,
        (__attribute__((address_space(3))) unsigned int*)l, 16, 0, 0);
#else
    *(bf16x8*)(l + lane * 8) = *(const bf16x8*)g;
#endif
}

__device__ __forceinline__ int swz(int r) { return r ^ (r >> 3); } // row-XOR bank swizzle

// ---------------------------------------------------------------------------
// fused fp32->bf16 conversion for all 5 tensors (grid.y selects region)
// ---------------------------------------------------------------------------
__global__ __launch_bounds__(256) void cvt_all(
    const float* __restrict__ x,  const float* __restrict__ wq,
    const float* __restrict__ wk, const float* __restrict__ wv,
    const float* __restrict__ wo,
    __hip_bfloat16* __restrict__ xb,  __hip_bfloat16* __restrict__ wqb,
    __hip_bfloat16* __restrict__ wkb, __hip_bfloat16* __restrict__ wvb,
    __hip_bfloat16* __restrict__ wob)
{
    const int reg = blockIdx.y;
    const float* src; __hip_bfloat16* dst; int n;
    if      (reg == 0) { src = x;  dst = xb;  n = 2 * SEQ * DIM; }
    else if (reg == 1) { src = wq; dst = wqb; n = DIM * DIM; }
    else if (reg == 2) { src = wk; dst = wkb; n = DIM * DIM; }
    else if (reg == 3) { src = wv; dst = wvb; n = DIM * DIM; }
    else               { src = wo; dst = wob; n = DIM * DIM; }
    const int i = (blockIdx.x * 256 + threadIdx.x) * 4;
    if (i < n) {
        float4 v = *(const float4*)(src + i);
        __hip_bfloat16 t[4];
        t[0] = __float2bfloat16(v.x); t[1] = __float2bfloat16(v.y);
        t[2] = __float2bfloat16(v.z); t[3] = __float2bfloat16(v.w);
        *(ushort4*)(dst + i) = *(ushort4*)t;
    }
}

// ---------------------------------------------------------------------------
// m97-style GEMM: 128x128 tile, BK=32, global_load_lds staging, 4 waves,
// each wave 64x64 (4x4 MFMA frags). Y = A * W^T + bias. grid.z selects W/Y.
// ---------------------------------------------------------------------------
template <typename OutT>
__global__ __launch_bounds__(256) void gemm128(
    const __hip_bfloat16* __restrict__ A,
    const __hip_bfloat16* __restrict__ W0, const __hip_bfloat16* __restrict__ W1,
    const __hip_bfloat16* __restrict__ W2,
    const float* __restrict__ b0, const float* __restrict__ b1,
    const float* __restrict__ b2,
    OutT* __restrict__ Y0, OutT* __restrict__ Y1, OutT* __restrict__ Y2,
    int M, int N, int K)
{
    __shared__ __align__(16) __hip_bfloat16 As[128 * 32];
    __shared__ __align__(16) __hip_bfloat16 Bs[128 * 32];

    const int z = blockIdx.z;
    const __hip_bfloat16* W = (z == 0) ? W0 : ((z == 1) ? W1 : W2);
    const float* bias = (z == 0) ? b0 : ((z == 1) ? b1 : b2);
    OutT* Y = (z == 0) ? Y0 : ((z == 1) ? Y1 : Y2);

    const int tid = threadIdx.x;
    const int wv = tid >> 6, lane = tid & 63;
    const int col16 = lane & 15, quad = lane >> 4;
    const int m0 = blockIdx.x * 128, n0 = blockIdx.y * 128;

    // staging: chunk c covers LDS bytes [c*16, c*16+16); c = (wv*2+j)*64 + lane
    const int c0i = (wv * 2) * 64 + lane, c1i = (wv * 2 + 1) * 64 + lane;
    const __hip_bfloat16* ga0 = A + (size_t)(m0 + (c0i >> 2)) * K + (c0i & 3) * 8;
    const __hip_bfloat16* ga1 = A + (size_t)(m0 + (c1i >> 2)) * K + (c1i & 3) * 8;
    const __hip_bfloat16* gb0 = W + (size_t)(n0 + (c0i >> 2)) * K + (c0i & 3) * 8;
    const __hip_bfloat16* gb1 = W + (size_t)(n0 + (c1i >> 2)) * K + (c1i & 3) * 8;
    __hip_bfloat16* la0 = As + (wv * 2) * 512;
    __hip_bfloat16* la1 = As + (wv * 2 + 1) * 512;
    __hip_bfloat16* lb0 = Bs + (wv * 2) * 512;
    __hip_bfloat16* lb1 = Bs + (wv * 2 + 1) * 512;

    const int wr = wv >> 1, wc = wv & 1;
    const __hip_bfloat16* ar = As + (wr * 64 + col16) * 32 + quad * 8;
    const __hip_bfloat16* br = Bs + (wc * 64 + col16) * 32 + quad * 8;

    f32x4 acc[16] = {};

    for (int k0 = 0; k0 < K; k0 += 32) {
        __syncthreads();
        stage16(ga0 + k0, la0, lane);
        stage16(ga1 + k0, la1, lane);
        stage16(gb0 + k0, lb0, lane);
        stage16(gb1 + k0, lb1, lane);
        __syncthreads();
        bf16x8 af[4], bfm[4];
#pragma unroll
        for (int mt = 0; mt < 4; ++mt) af[mt] = *(const bf16x8*)(ar + mt * 16 * 32);
#pragma unroll
        for (int nt = 0; nt < 4; ++nt) bfm[nt] = *(const bf16x8*)(br + nt * 16 * 32);
#pragma unroll
        for (int mt = 0; mt < 4; ++mt)
#pragma unroll
            for (int nt = 0; nt < 4; ++nt)
                acc[mt * 4 + nt] = MFMA16(af[mt], bfm[nt], acc[mt * 4 + nt]);
    }

#pragma unroll
    for (int nt = 0; nt < 4; ++nt) {
        const int n = n0 + wc * 64 + nt * 16 + col16;
        const float bv = bias[n];
#pragma unroll
        for (int mt = 0; mt < 4; ++mt) {
#pragma unroll
            for (int r = 0; r < 4; ++r) {
                const int m = m0 + wr * 64 + mt * 16 + quad * 4 + r;
                Y[(size_t)m * N + n] = (OutT)(acc[mt * 4 + nt][r] + bv);
            }
        }
    }
}

// ---------------------------------------------------------------------------
// Attention. Block = 256 thr = 4 waves over 32 q-rows of one (b,h):
//   wave w: row-group g=w&1 (16 rows), j-half = w>>1 (512 js each).
// Per j64-iter: stage transposed V (row-swizzled, paired b32 writes),
// QK^T MFMA -> multi-freq sin transform -> sigmoid -> Pl (row-swizzled)
// -> PV MFMA. Halves combined through LDS at the end (normalization linear).
// ---------------------------------------------------------------------------
__global__ __launch_bounds__(256) void attn_kernel(
    const __hip_bfloat16* __restrict__ Q,
    const __hip_bfloat16* __restrict__ K,
    const __hip_bfloat16* __restrict__ V,
    const float* __restrict__ alpha, const float* __restrict__ phi,
    const float* __restrict__ temperature,
    __hip_bfloat16* __restrict__ AO)
{
    // smem: Vt [2 halves][64 d][pitch 72]  (18432 B), Pl [4 waves][16][40] (5120 B)
    // combine phase aliases Vt region: Ocomb [2][16][68] f32 + Dl [32] f32
    __shared__ __align__(16) char smem[18432 + 5120];
    __hip_bfloat16* VtBase = (__hip_bfloat16*)smem;
    __hip_bfloat16* PlBase = (__hip_bfloat16*)(smem + 18432);
    float* Ocomb = (float*)smem;                 // [2][16][68]
    float* Dl    = (float*)(smem + 2 * 16 * 68 * 4);

    const int tid = threadIdx.x;
    const int wv = tid >> 6, lane = tid & 63;
    const int col16 = lane & 15, quad = lane >> 4;
    const int g = wv & 1, half = wv >> 1;

    const int bh = blockIdx.y, b = bh >> 4, h = bh & 15;
    const int i0 = blockIdx.x * 32 + g * 16;
    const size_t base = ((size_t)b * SEQ) * DIM + (size_t)h * HD;

    const float tempv = fabsf(temperature[0]) + 0.1f;
    const float simscale = 1.0f / (8.0f * tempv);
    const float freqs[5] = {31.0f, 37.0f, 41.0f, 43.0f, 47.0f};
    float al[5], prev[5], crev[5];
#pragma unroll
    for (int f = 0; f < 5; ++f) {
        al[f]   = alpha[h * 5 + f];
        prev[f] = phi[h * 5 + f] * 0.15915494309f;   // phi / 2pi
        crev[f] = simscale / freqs[f];               // (1/freq)*simscale, revolutions
    }

    // Q fragments (rows i0..i0+15, k=0..63)
    const __hip_bfloat16* qrow = Q + base + (size_t)(i0 + col16) * DIM + quad * 8;
    const bf16x8 qa0 = *(const bf16x8*)(qrow);
    const bf16x8 qa1 = *(const bf16x8*)(qrow + 32);

    // Vt staging setup: 128 threads per half; thread: 8 d-rows x 2 j-pairs x 2 j-blocks
    const int tl = tid & 127;
    const int sc0 = (tl & 7) * 8;       // d base
    const int sx  = tl & 7;             // swizzle xor for these rows
    const int jj0 = (tl >> 3) * 2;      // 0,2,..,30
    __hip_bfloat16* VtH = VtBase + half * 64 * 72;
    __hip_bfloat16* rowp[8];
#pragma unroll
    for (int e = 0; e < 8; ++e) rowp[e] = VtH + (sc0 + (e ^ sx)) * 72;

    // Vt B-frag read pointers (per wave)
    const __hip_bfloat16* vrd[4];
#pragma unroll
    for (int t = 0; t < 4; ++t)
        vrd[t] = VtH + swz(t * 16 + col16) * 72 + quad * 8;

    // Pl pointers (per wave)
    __hip_bfloat16* PlW = PlBase + wv * 16 * 40;
    const __hip_bfloat16* plr = PlW + swz(col16) * 40 + quad * 8;
    __hip_bfloat16* plw[4];
#pragma unroll
    for (int r = 0; r < 4; ++r) plw[r] = PlW + swz(quad * 4 + r) * 40;

    f32x4 o[4] = {};
    float denom[4] = {0.f, 0.f, 0.f, 0.f};

    for (int it = 0; it < 8; ++it) {
        const int j0 = half * 512 + it * 64;
        __syncthreads();   // WAR: previous iter's Vt reads done
        // stage transposed V tile (64 j x 64 d), paired b32 writes
#pragma unroll
        for (int s = 0; s < 2; ++s) {
            const __hip_bfloat16* vp = V + base + (size_t)(j0 + jj0 + 32 * s) * DIM + sc0;
            bf16x8 va = *(const bf16x8*)(vp);
            bf16x8 vb2 = *(const bf16x8*)(vp + DIM);
#pragma unroll
            for (int e = 0; e < 8; ++e) {
                unsigned pk = ((unsigned)(unsigned short)va[e]) |
                              (((unsigned)(unsigned short)vb2[e]) << 16);
                *(unsigned*)(rowp[e] + jj0 + 32 * s) = pk;
            }
        }
        __syncthreads();

#pragma unroll
        for (int sub = 0; sub < 2; ++sub) {
#pragma unroll
            for (int s2 = 0; s2 < 2; ++s2) {
                const int js = j0 + (sub * 2 + s2) * 16;
                const __hip_bfloat16* krow = K + base + (size_t)(js + col16) * DIM + quad * 8;
                bf16x8 kb0 = *(const bf16x8*)(krow);
                bf16x8 kb1 = *(const bf16x8*)(krow + 32);
                f32x4 sa = {};
                sa = MFMA16(qa0, kb0, sa);
                sa = MFMA16(qa1, kb1, sa);
#pragma unroll
                for (int r = 0; r < 4; ++r) {
                    float sc = 0.f;
#pragma unroll
                    for (int f = 0; f < 5; ++f)
                        sc += al[f] * SIN_REV(sa[r] * crev[f] + prev[f]);
                    const float w = FAST_RCP(1.0f + __expf(-sc));
                    denom[r] += w;
                    plw[r][s2 * 16 + col16] = __float2bfloat16(w);
                }
            }
            // PV over this 32-j block
            bf16x8 pa = *(const bf16x8*)plr;
#pragma unroll
            for (int t = 0; t < 4; ++t) {
                bf16x8 vb = *(const bf16x8*)(vrd[t] + 32 * sub);
                o[t] = MFMA16(pa, vb, o[t]);
            }
        }
    }

    // per-row denom within this half (butterfly over col16)
#pragma unroll
    for (int r = 0; r < 4; ++r) {
        float d = denom[r];
        d += __shfl_xor(d, 1);
        d += __shfl_xor(d, 2);
        d += __shfl_xor(d, 4);
        d += __shfl_xor(d, 8);
        denom[r] = d;
    }

    __syncthreads();   // all loop LDS reads done; safe to alias Vt region
    if (half == 1) {
#pragma unroll
        for (int t = 0; t < 4; ++t)
#pragma unroll
            for (int r = 0; r < 4; ++r)
                Ocomb[(g * 16 + quad * 4 + r) * 68 + t * 16 + col16] = o[t][r];
        if (col16 == 0) {
#pragma unroll
            for (int r = 0; r < 4; ++r) Dl[g * 16 + quad * 4 + r] = denom[r];
        }
    }
    __syncthreads();
    if (half == 0) {
#pragma unroll
        for (int r = 0; r < 4; ++r)
            denom[r] = denom[r] + Dl[g * 16 + quad * 4 + r] + 1e-10f;
#pragma unroll
        for (int t = 0; t < 4; ++t) {
#pragma unroll
            for (int r = 0; r < 4; ++r) {
                const float val =
                    (o[t][r] + Ocomb[(g * 16 + quad * 4 + r) * 68 + t * 16 + col16]) / denom[r];
                const size_t row = (size_t)b * SEQ + i0 + quad * 4 + r;
                AO[row * DIM + h * HD + t * 16 + col16] = __float2bfloat16(val);
            }
        }
    }
}

// ---------------------------------------------------------------------------
// LayerNorm over last dim (1024), eps=1e-5, biased variance. fp32 in/out.
// ---------------------------------------------------------------------------
__global__ __launch_bounds__(256) void ln_kernel(
    const float* __restrict__ Yp,
    const float* __restrict__ gamma,
    const float* __restrict__ beta,
    float* __restrict__ out)
{
    const int row = blockIdx.x;
    const float* y = Yp + (size_t)row * DIM;

    float v[4];
    float s = 0.f, s2 = 0.f;
#pragma unroll
    for (int e = 0; e < 4; ++e) {
        v[e] = y[threadIdx.x + e * 256];
        s += v[e];
        s2 += v[e] * v[e];
    }
#pragma unroll
    for (int off = 1; off < 64; off <<= 1) {
        s  += __shfl_xor(s, off);
        s2 += __shfl_xor(s2, off);
    }
    __shared__ float ps[4], ps2[4];
    const int wave = threadIdx.x >> 6;
    if ((threadIdx.x & 63) == 0) { ps[wave] = s; ps2[wave] = s2; }
    __syncthreads();
    s  = ps[0] + ps[1] + ps[2] + ps[3];
    s2 = ps2[0] + ps2[1] + ps2[2] + ps2[3];

    const float mu   = s * (1.0f / DIM);
    const float var  = s2 * (1.0f / DIM) - mu * mu;
    const float rstd = rsqrtf(var + 1e-5f);

#pragma unroll
    for (int e = 0; e < 4; ++e) {
        const int idx = threadIdx.x + e * 256;
        out[(size_t)row * DIM + idx] =
            (v[e] - mu) * rstd * gamma[idx] + beta[idx];
    }
}

// ---------------------------------------------------------------------------
extern "C" void kernel_launch(void* const* d_in, const int* in_sizes, int n_in,
                              void* d_out, int out_size, void* d_ws, size_t ws_size,
                              hipStream_t stream)
{
    const float* x     = (const float*)d_in[0];
    const float* Wq    = (const float*)d_in[1];
    const float* bq    = (const float*)d_in[2];
    const float* Wk    = (const float*)d_in[3];
    const float* bk    = (const float*)d_in[4];
    const float* Wv    = (const float*)d_in[5];
    const float* bv    = (const float*)d_in[6];
    const float* Wo    = (const float*)d_in[7];
    const float* bo    = (const float*)d_in[8];
    const float* alpha = (const float*)d_in[9];
    const float* phi   = (const float*)d_in[10];
    const float* temp  = (const float*)d_in[11];
    const float* gamma = (const float*)d_in[12];
    const float* beta  = (const float*)d_in[13];

    float* out = (float*)d_out;

    const int B = 2;
    const int M = B * SEQ;                 // 2048

    // ws layout (same 28MB footprint as R2, which fit):
    //   [0,4M)   xb    [4,6M) Wqb   [6,8M) Wkb   [8,10M) Wvb   [10,12M) Wob
    //   [12,16M) Qb    [16,20M) Kb  [20,24M) Vb  [24,28M) AO
    //   Yp (fp32 8MB) aliases [0,8M) — xb/Wqb/Wkb dead by O-proj.
    char* wsb = (char*)d_ws;
    __hip_bfloat16* xb  = (__hip_bfloat16*)(wsb + 0);
    __hip_bfloat16* Wqb = (__hip_bfloat16*)(wsb + (4u  << 20));
    __hip_bfloat16* Wkb = (__hip_bfloat16*)(wsb + (6u  << 20));
    __hip_bfloat16* Wvb = (__hip_bfloat16*)(wsb + (8u  << 20));
    __hip_bfloat16* Wob = (__hip_bfloat16*)(wsb + (10u << 20));
    __hip_bfloat16* Qb  = (__hip_bfloat16*)(wsb + (12u << 20));
    __hip_bfloat16* Kb  = (__hip_bfloat16*)(wsb + (16u << 20));
    __hip_bfloat16* Vb  = (__hip_bfloat16*)(wsb + (20u << 20));
    __hip_bfloat16* AO  = (__hip_bfloat16*)(wsb + (24u << 20));
    float*          Yp  = (float*)(wsb + 0);

    hipLaunchKernelGGL(cvt_all, dim3(2048, 5), dim3(256), 0, stream,
                       x, Wq, Wk, Wv, Wo, xb, Wqb, Wkb, Wvb, Wob);

    // QKV fused: grid.z picks weight/output
    hipLaunchKernelGGL((gemm128<__hip_bfloat16>), dim3(M / 128, DIM / 128, 3), dim3(256), 0, stream,
                       xb, Wqb, Wkb, Wvb, bq, bk, bv, Qb, Kb, Vb, M, DIM, DIM);

    hipLaunchKernelGGL(attn_kernel, dim3(SEQ / 32, B * NH), dim3(256), 0, stream,
                       Qb, Kb, Vb, alpha, phi, temp, AO);

    hipLaunchKernelGGL((gemm128<float>), dim3(M / 128, DIM / 128, 1), dim3(256), 0, stream,
                       AO, Wob, Wob, Wob, bo, bo, bo, Yp, Yp, Yp, M, DIM, DIM);

    hipLaunchKernelGGL(ln_kernel, dim3(M), dim3(256), 0, stream, Yp, gamma, beta, out);
}

// Round 4
// 181.313 us; speedup vs baseline: 1.9055x; 1.0932x over previous
//
#include <hip/hip_runtime.h>
#include <hip/hip_bf16.h>

typedef short bf16x8 __attribute__((ext_vector_type(8)));
typedef float f32x4 __attribute__((ext_vector_type(4)));

#define MFMA16(a, b, c) __builtin_amdgcn_mfma_f32_16x16x32_bf16(a, b, c, 0, 0, 0)

static constexpr int SEQ = 1024;
static constexpr int DIM = 1024;
static constexpr int NH = 16;
static constexpr int HD = 64;

#if __has_builtin(__builtin_amdgcn_sinf)
#define SIN_REV(x) __builtin_amdgcn_sinf(x)      // sin(2*pi*x), x in revolutions
#else
#define SIN_REV(x) __sinf((x) * 6.28318530718f)
#endif

#if __has_builtin(__builtin_amdgcn_rcpf)
#define FAST_RCP(x) __builtin_amdgcn_rcpf(x)
#else
#define FAST_RCP(x) (1.0f / (x))
#endif

#if __has_builtin(__builtin_amdgcn_exp2f)
#define EXP2F(x) __builtin_amdgcn_exp2f(x)
#else
#define EXP2F(x) exp2f(x)
#endif

// async 16B/lane global->LDS; lds dest = base + lane*16 bytes (HW semantics)
__device__ __forceinline__ void stage16(const __hip_bfloat16* g, __hip_bfloat16* l, int lane) {
#if __has_builtin(__builtin_amdgcn_global_load_lds)
    __builtin_amdgcn_global_load_lds(
        (const __attribute__((address_space(1))) unsigned int*)g,
        (__attribute__((address_space(3))) unsigned int*)l, 16, 0, 0);
#else
    *(bf16x8*)(l + lane * 8) = *(const bf16x8*)g;
#endif
}

__device__ __forceinline__ int swz(int r) { return r ^ (r >> 3); } // row-XOR bank swizzle

// ---------------------------------------------------------------------------
// fused fp32->bf16 conversion for all 5 tensors (grid.y selects region)
// ---------------------------------------------------------------------------
__global__ __launch_bounds__(256) void cvt_all(
    const float* __restrict__ x,  const float* __restrict__ wq,
    const float* __restrict__ wk, const float* __restrict__ wv,
    const float* __restrict__ wo,
    __hip_bfloat16* __restrict__ xb,  __hip_bfloat16* __restrict__ wqb,
    __hip_bfloat16* __restrict__ wkb, __hip_bfloat16* __restrict__ wvb,
    __hip_bfloat16* __restrict__ wob)
{
    const int reg = blockIdx.y;
    const float* src; __hip_bfloat16* dst; int n;
    if      (reg == 0) { src = x;  dst = xb;  n = 2 * SEQ * DIM; }
    else if (reg == 1) { src = wq; dst = wqb; n = DIM * DIM; }
    else if (reg == 2) { src = wk; dst = wkb; n = DIM * DIM; }
    else if (reg == 3) { src = wv; dst = wvb; n = DIM * DIM; }
    else               { src = wo; dst = wob; n = DIM * DIM; }
    const int i = (blockIdx.x * 256 + threadIdx.x) * 4;
    if (i < n) {
        float4 v = *(const float4*)(src + i);
        __hip_bfloat16 t[4];
        t[0] = __float2bfloat16(v.x); t[1] = __float2bfloat16(v.y);
        t[2] = __float2bfloat16(v.z); t[3] = __float2bfloat16(v.w);
        *(ushort4*)(dst + i) = *(ushort4*)t;
    }
}

// ---------------------------------------------------------------------------
// GEMM 64x128 tile, BK=32, global_load_lds staging, 4 waves (wave = 32x64).
// QKV: grid.z in {0,1,2} selects W/bias/Y. Y = A*W^T + bias, bf16 out.
// ---------------------------------------------------------------------------
__global__ __launch_bounds__(256) void gemm_qkv(
    const __hip_bfloat16* __restrict__ A,
    const __hip_bfloat16* __restrict__ W0, const __hip_bfloat16* __restrict__ W1,
    const __hip_bfloat16* __restrict__ W2,
    const float* __restrict__ b0, const float* __restrict__ b1,
    const float* __restrict__ b2,
    __hip_bfloat16* __restrict__ Y0, __hip_bfloat16* __restrict__ Y1,
    __hip_bfloat16* __restrict__ Y2,
    int M, int N, int K)
{
    __shared__ __align__(16) __hip_bfloat16 As[64 * 32];
    __shared__ __align__(16) __hip_bfloat16 Ws[128 * 32];

    const int z = blockIdx.z;
    const __hip_bfloat16* W = (z == 0) ? W0 : ((z == 1) ? W1 : W2);
    const float* bias = (z == 0) ? b0 : ((z == 1) ? b1 : b2);
    __hip_bfloat16* Y = (z == 0) ? Y0 : ((z == 1) ? Y1 : Y2);

    const int tid = threadIdx.x;
    const int wv = tid >> 6, lane = tid & 63;
    const int col16 = lane & 15, quad = lane >> 4;
    const int m0 = blockIdx.x * 64, n0 = blockIdx.y * 128;

    // staging chunk indices
    const int ca = wv * 64 + lane;            // A chunk 0..255
    const int cb0 = ca, cb1 = 256 + ca;       // W chunks 0..511
    const __hip_bfloat16* ga  = A + (size_t)(m0 + (ca  >> 2)) * K + (ca  & 3) * 8;
    const __hip_bfloat16* gb0 = W + (size_t)(n0 + (cb0 >> 2)) * K + (cb0 & 3) * 8;
    const __hip_bfloat16* gb1 = W + (size_t)(n0 + (cb1 >> 2)) * K + (cb1 & 3) * 8;
    __hip_bfloat16* la  = As + wv * 512;
    __hip_bfloat16* lb0 = Ws + wv * 512;
    __hip_bfloat16* lb1 = Ws + 2048 + wv * 512;

    const int wr = wv >> 1, wc = wv & 1;
    const __hip_bfloat16* ar = As + (wr * 32 + col16) * 32 + quad * 8;
    const __hip_bfloat16* br = Ws + (wc * 64 + col16) * 32 + quad * 8;

    f32x4 acc[8] = {};

    for (int k0 = 0; k0 < K; k0 += 32) {
        __syncthreads();
        stage16(ga  + k0, la,  lane);
        stage16(gb0 + k0, lb0, lane);
        stage16(gb1 + k0, lb1, lane);
        __syncthreads();
        bf16x8 af[2], bfm[4];
#pragma unroll
        for (int mt = 0; mt < 2; ++mt) af[mt] = *(const bf16x8*)(ar + mt * 16 * 32);
#pragma unroll
        for (int nt = 0; nt < 4; ++nt) bfm[nt] = *(const bf16x8*)(br + nt * 16 * 32);
#pragma unroll
        for (int mt = 0; mt < 2; ++mt)
#pragma unroll
            for (int nt = 0; nt < 4; ++nt)
                acc[mt * 4 + nt] = MFMA16(af[mt], bfm[nt], acc[mt * 4 + nt]);
    }

#pragma unroll
    for (int nt = 0; nt < 4; ++nt) {
        const int n = n0 + wc * 64 + nt * 16 + col16;
        const float bv = bias[n];
#pragma unroll
        for (int mt = 0; mt < 2; ++mt) {
#pragma unroll
            for (int r = 0; r < 4; ++r) {
                const int m = m0 + wr * 32 + mt * 16 + quad * 4 + r;
                Y[(size_t)m * N + n] = __float2bfloat16(acc[mt * 4 + nt][r] + bv);
            }
        }
    }
}

// ---------------------------------------------------------------------------
// O-proj with split-K: grid.z in {0,1} selects K-half and output partial.
// Partial 0 carries the bias; partials summed in ln_kernel. fp32 out.
// ---------------------------------------------------------------------------
__global__ __launch_bounds__(256) void gemm_osplit(
    const __hip_bfloat16* __restrict__ A,
    const __hip_bfloat16* __restrict__ W,
    const float* __restrict__ bias,
    float* __restrict__ Y0, float* __restrict__ Y1,
    int M, int N, int K)
{
    __shared__ __align__(16) __hip_bfloat16 As[64 * 32];
    __shared__ __align__(16) __hip_bfloat16 Ws[128 * 32];

    const int z = blockIdx.z;
    float* Y = (z == 0) ? Y0 : Y1;
    const int kb = z * 512;

    const int tid = threadIdx.x;
    const int wv = tid >> 6, lane = tid & 63;
    const int col16 = lane & 15, quad = lane >> 4;
    const int m0 = blockIdx.x * 64, n0 = blockIdx.y * 128;

    const int ca = wv * 64 + lane;
    const int cb1 = 256 + ca;
    const __hip_bfloat16* ga  = A + (size_t)(m0 + (ca  >> 2)) * K + (ca  & 3) * 8 + kb;
    const __hip_bfloat16* gb0 = W + (size_t)(n0 + (ca  >> 2)) * K + (ca  & 3) * 8 + kb;
    const __hip_bfloat16* gb1 = W + (size_t)(n0 + (cb1 >> 2)) * K + (cb1 & 3) * 8 + kb;
    __hip_bfloat16* la  = As + wv * 512;
    __hip_bfloat16* lb0 = Ws + wv * 512;
    __hip_bfloat16* lb1 = Ws + 2048 + wv * 512;

    const int wr = wv >> 1, wc = wv & 1;
    const __hip_bfloat16* ar = As + (wr * 32 + col16) * 32 + quad * 8;
    const __hip_bfloat16* br = Ws + (wc * 64 + col16) * 32 + quad * 8;

    f32x4 acc[8] = {};

    for (int k0 = 0; k0 < 512; k0 += 32) {
        __syncthreads();
        stage16(ga  + k0, la,  lane);
        stage16(gb0 + k0, lb0, lane);
        stage16(gb1 + k0, lb1, lane);
        __syncthreads();
        bf16x8 af[2], bfm[4];
#pragma unroll
        for (int mt = 0; mt < 2; ++mt) af[mt] = *(const bf16x8*)(ar + mt * 16 * 32);
#pragma unroll
        for (int nt = 0; nt < 4; ++nt) bfm[nt] = *(const bf16x8*)(br + nt * 16 * 32);
#pragma unroll
        for (int mt = 0; mt < 2; ++mt)
#pragma unroll
            for (int nt = 0; nt < 4; ++nt)
                acc[mt * 4 + nt] = MFMA16(af[mt], bfm[nt], acc[mt * 4 + nt]);
    }

#pragma unroll
    for (int nt = 0; nt < 4; ++nt) {
        const int n = n0 + wc * 64 + nt * 16 + col16;
        const float bv = (z == 0) ? bias[n] : 0.0f;
#pragma unroll
        for (int mt = 0; mt < 2; ++mt) {
#pragma unroll
            for (int r = 0; r < 4; ++r) {
                const int m = m0 + wr * 32 + mt * 16 + quad * 4 + r;
                Y[(size_t)m * N + n] = acc[mt * 4 + nt][r] + bv;
            }
        }
    }
}

// ---------------------------------------------------------------------------
// Attention. Block = 256 thr = 4 waves over 32 q-rows of one (b,h):
//   wave w: row-group g=w&1 (16 rows), j-half = w>>1 (512 js each).
// Per j64-iter: stage transposed V (row-swizzled), preload all K-frags,
// QK^T MFMA -> multi-freq sin transform -> sigmoid (exp2, log2e folded into
// alpha) -> Pl (row-swizzled) -> PV MFMA. Halves combined via LDS at end.
// ---------------------------------------------------------------------------
__global__ __launch_bounds__(256) void attn_kernel(
    const __hip_bfloat16* __restrict__ Q,
    const __hip_bfloat16* __restrict__ K,
    const __hip_bfloat16* __restrict__ V,
    const float* __restrict__ alpha, const float* __restrict__ phi,
    const float* __restrict__ temperature,
    __hip_bfloat16* __restrict__ AO)
{
    __shared__ __align__(16) char smem[18432 + 5120];
    __hip_bfloat16* VtBase = (__hip_bfloat16*)smem;
    __hip_bfloat16* PlBase = (__hip_bfloat16*)(smem + 18432);
    float* Ocomb = (float*)smem;                 // [2][16][68]
    float* Dl    = (float*)(smem + 2 * 16 * 68 * 4);

    const int tid = threadIdx.x;
    const int wv = tid >> 6, lane = tid & 63;
    const int col16 = lane & 15, quad = lane >> 4;
    const int g = wv & 1, half = wv >> 1;

    const int bh = blockIdx.y, b = bh >> 4, h = bh & 15;
    const int i0 = blockIdx.x * 32 + g * 16;
    const size_t base = ((size_t)b * SEQ) * DIM + (size_t)h * HD;

    const float tempv = fabsf(temperature[0]) + 0.1f;
    const float simscale = 1.0f / (8.0f * tempv);
    const float freqs[5] = {31.0f, 37.0f, 41.0f, 43.0f, 47.0f};
    float al[5], prev[5], crev[5];
#pragma unroll
    for (int f = 0; f < 5; ++f) {
        al[f]   = alpha[h * 5 + f] * 1.44269504089f;   // fold log2(e)
        prev[f] = phi[h * 5 + f] * 0.15915494309f;     // phi / 2pi
        crev[f] = simscale / freqs[f];                 // revolutions per sim unit
    }

    const __hip_bfloat16* qrow = Q + base + (size_t)(i0 + col16) * DIM + quad * 8;
    const bf16x8 qa0 = *(const bf16x8*)(qrow);
    const bf16x8 qa1 = *(const bf16x8*)(qrow + 32);

    const __hip_bfloat16* kbase = K + base + (size_t)col16 * DIM + quad * 8;

    // Vt staging: 128 threads per half; thread: 8 d-rows x 2 j-pairs x 2 blocks
    const int tl = tid & 127;
    const int sc0 = (tl & 7) * 8;
    const int sx  = tl & 7;
    const int jj0 = (tl >> 3) * 2;
    __hip_bfloat16* VtH = VtBase + half * 64 * 72;
    __hip_bfloat16* rowp[8];
#pragma unroll
    for (int e = 0; e < 8; ++e) rowp[e] = VtH + (sc0 + (e ^ sx)) * 72;

    const __hip_bfloat16* vrd[4];
#pragma unroll
    for (int t = 0; t < 4; ++t)
        vrd[t] = VtH + swz(t * 16 + col16) * 72 + quad * 8;

    __hip_bfloat16* PlW = PlBase + wv * 16 * 40;
    const __hip_bfloat16* plr = PlW + swz(col16) * 40 + quad * 8;
    __hip_bfloat16* plw[4];
#pragma unroll
    for (int r = 0; r < 4; ++r) plw[r] = PlW + swz(quad * 4 + r) * 40;

    f32x4 o[4] = {};
    float denom[4] = {0.f, 0.f, 0.f, 0.f};

    for (int it = 0; it < 8; ++it) {
        const int j0 = half * 512 + it * 64;
        __syncthreads();
#pragma unroll
        for (int s = 0; s < 2; ++s) {
            const __hip_bfloat16* vp = V + base + (size_t)(j0 + jj0 + 32 * s) * DIM + sc0;
            bf16x8 va  = *(const bf16x8*)(vp);
            bf16x8 vb2 = *(const bf16x8*)(vp + DIM);
#pragma unroll
            for (int e = 0; e < 8; ++e) {
                unsigned pk = ((unsigned)(unsigned short)va[e]) |
                              (((unsigned)(unsigned short)vb2[e]) << 16);
                *(unsigned*)(rowp[e] + jj0 + 32 * s) = pk;
            }
        }
        // preload ALL K fragments for this j64 before the transform loops
        bf16x8 kf[4][2];
#pragma unroll
        for (int u = 0; u < 4; ++u) {
            const __hip_bfloat16* kp = kbase + (size_t)(j0 + u * 16) * DIM;
            kf[u][0] = *(const bf16x8*)(kp);
            kf[u][1] = *(const bf16x8*)(kp + 32);
        }
        __syncthreads();

#pragma unroll
        for (int sub = 0; sub < 2; ++sub) {
#pragma unroll
            for (int s2 = 0; s2 < 2; ++s2) {
                const int u = sub * 2 + s2;
                f32x4 sa = {};
                sa = MFMA16(qa0, kf[u][0], sa);
                sa = MFMA16(qa1, kf[u][1], sa);
#pragma unroll
                for (int r = 0; r < 4; ++r) {
                    float sc = 0.f;
#pragma unroll
                    for (int f = 0; f < 5; ++f)
                        sc += al[f] * SIN_REV(sa[r] * crev[f] + prev[f]);
                    const float w = FAST_RCP(1.0f + EXP2F(-sc));
                    denom[r] += w;
                    plw[r][s2 * 16 + col16] = __float2bfloat16(w);
                }
            }
            bf16x8 pa = *(const bf16x8*)plr;
#pragma unroll
            for (int t = 0; t < 4; ++t) {
                bf16x8 vb = *(const bf16x8*)(vrd[t] + 32 * sub);
                o[t] = MFMA16(pa, vb, o[t]);
            }
        }
    }

#pragma unroll
    for (int r = 0; r < 4; ++r) {
        float d = denom[r];
        d += __shfl_xor(d, 1);
        d += __shfl_xor(d, 2);
        d += __shfl_xor(d, 4);
        d += __shfl_xor(d, 8);
        denom[r] = d;
    }

    __syncthreads();
    if (half == 1) {
#pragma unroll
        for (int t = 0; t < 4; ++t)
#pragma unroll
            for (int r = 0; r < 4; ++r)
                Ocomb[(g * 16 + quad * 4 + r) * 68 + t * 16 + col16] = o[t][r];
        if (col16 == 0) {
#pragma unroll
            for (int r = 0; r < 4; ++r) Dl[g * 16 + quad * 4 + r] = denom[r];
        }
    }
    __syncthreads();
    if (half == 0) {
#pragma unroll
        for (int r = 0; r < 4; ++r)
            denom[r] = denom[r] + Dl[g * 16 + quad * 4 + r] + 1e-10f;
#pragma unroll
        for (int t = 0; t < 4; ++t) {
#pragma unroll
            for (int r = 0; r < 4; ++r) {
                const float val =
                    (o[t][r] + Ocomb[(g * 16 + quad * 4 + r) * 68 + t * 16 + col16]) / denom[r];
                const size_t row = (size_t)b * SEQ + i0 + quad * 4 + r;
                AO[row * DIM + h * HD + t * 16 + col16] = __float2bfloat16(val);
            }
        }
    }
}

// ---------------------------------------------------------------------------
// LayerNorm over last dim (1024), sums the two split-K partials of O-proj.
// ---------------------------------------------------------------------------
__global__ __launch_bounds__(256) void ln_kernel(
    const float* __restrict__ Yp0,
    const float* __restrict__ Yp1,
    const float* __restrict__ gamma,
    const float* __restrict__ beta,
    float* __restrict__ out)
{
    const int row = blockIdx.x;
    const float* y0 = Yp0 + (size_t)row * DIM;
    const float* y1 = Yp1 + (size_t)row * DIM;

    float v[4];
    float s = 0.f, s2 = 0.f;
#pragma unroll
    for (int e = 0; e < 4; ++e) {
        const int idx = threadIdx.x + e * 256;
        v[e] = y0[idx] + y1[idx];
        s += v[e];
        s2 += v[e] * v[e];
    }
#pragma unroll
    for (int off = 1; off < 64; off <<= 1) {
        s  += __shfl_xor(s, off);
        s2 += __shfl_xor(s2, off);
    }
    __shared__ float ps[4], ps2[4];
    const int wave = threadIdx.x >> 6;
    if ((threadIdx.x & 63) == 0) { ps[wave] = s; ps2[wave] = s2; }
    __syncthreads();
    s  = ps[0] + ps[1] + ps[2] + ps[3];
    s2 = ps2[0] + ps2[1] + ps2[2] + ps2[3];

    const float mu   = s * (1.0f / DIM);
    const float var  = s2 * (1.0f / DIM) - mu * mu;
    const float rstd = rsqrtf(var + 1e-5f);

#pragma unroll
    for (int e = 0; e < 4; ++e) {
        const int idx = threadIdx.x + e * 256;
        out[(size_t)row * DIM + idx] =
            (v[e] - mu) * rstd * gamma[idx] + beta[idx];
    }
}

// ---------------------------------------------------------------------------
extern "C" void kernel_launch(void* const* d_in, const int* in_sizes, int n_in,
                              void* d_out, int out_size, void* d_ws, size_t ws_size,
                              hipStream_t stream)
{
    const float* x     = (const float*)d_in[0];
    const float* Wq    = (const float*)d_in[1];
    const float* bq    = (const float*)d_in[2];
    const float* Wk    = (const float*)d_in[3];
    const float* bk    = (const float*)d_in[4];
    const float* Wv    = (const float*)d_in[5];
    const float* bv    = (const float*)d_in[6];
    const float* Wo    = (const float*)d_in[7];
    const float* bo    = (const float*)d_in[8];
    const float* alpha = (const float*)d_in[9];
    const float* phi   = (const float*)d_in[10];
    const float* temp  = (const float*)d_in[11];
    const float* gamma = (const float*)d_in[12];
    const float* beta  = (const float*)d_in[13];

    float* out = (float*)d_out;

    const int B = 2;
    const int M = B * SEQ;                 // 2048

    // ws layout (MB):
    //   [0,4)   xb    [4,6) Wqb   [6,8) Wkb   [8,10) Wvb   [10,12) Wob
    //   [12,16) Qb    [16,20) Kb  [20,24) Vb  [24,28) AO
    //   Yp0 (fp32 8MB) aliases [0,8)  — xb/Wqb/Wkb dead by O-proj
    //   Yp1 (fp32 8MB) aliases [12,20) — Qb/Kb dead by O-proj
    char* wsb = (char*)d_ws;
    __hip_bfloat16* xb  = (__hip_bfloat16*)(wsb + 0);
    __hip_bfloat16* Wqb = (__hip_bfloat16*)(wsb + (4u  << 20));
    __hip_bfloat16* Wkb = (__hip_bfloat16*)(wsb + (6u  << 20));
    __hip_bfloat16* Wvb = (__hip_bfloat16*)(wsb + (8u  << 20));
    __hip_bfloat16* Wob = (__hip_bfloat16*)(wsb + (10u << 20));
    __hip_bfloat16* Qb  = (__hip_bfloat16*)(wsb + (12u << 20));
    __hip_bfloat16* Kb  = (__hip_bfloat16*)(wsb + (16u << 20));
    __hip_bfloat16* Vb  = (__hip_bfloat16*)(wsb + (20u << 20));
    __hip_bfloat16* AO  = (__hip_bfloat16*)(wsb + (24u << 20));
    float*          Yp0 = (float*)(wsb + 0);
    float*          Yp1 = (float*)(wsb + (12u << 20));

    hipLaunchKernelGGL(cvt_all, dim3(2048, 5), dim3(256), 0, stream,
                       x, Wq, Wk, Wv, Wo, xb, Wqb, Wkb, Wvb, Wob);

    hipLaunchKernelGGL(gemm_qkv, dim3(M / 64, DIM / 128, 3), dim3(256), 0, stream,
                       xb, Wqb, Wkb, Wvb, bq, bk, bv, Qb, Kb, Vb, M, DIM, DIM);

    hipLaunchKernelGGL(attn_kernel, dim3(SEQ / 32, B * NH), dim3(256), 0, stream,
                       Qb, Kb, Vb, alpha, phi, temp, AO);

    hipLaunchKernelGGL(gemm_osplit, dim3(M / 64, DIM / 128, 2), dim3(256), 0, stream,
                       AO, Wob, bo, Yp0, Yp1, M, DIM, DIM);

    hipLaunchKernelGGL(ln_kernel, dim3(M), dim3(256), 0, stream,
                       Yp0, Yp1, gamma, beta, out);
}